// Round 1
// baseline (189.237 us; speedup 1.0000x reference)
//
#include <hip/hip_runtime.h>

// YOLOv7 P3 head (stride 8): B=16, A=3, NC=80, H=W=80.
// Input  (b, a*85, h, w) channel-major fp32.
// Output (b, a*h*w, 85)  fp32: [px,py,pw,ph,conf,cls*80].
//
// One block per (b,a,y): output block = 6800 contiguous floats at bid*6800.
// Phase 1: coalesced scalar global loads (ch-major) -> elementwise transform
//          -> LDS in output order lds[x*85+ch] (bank stride 21: conflict-free).
// Phase 2: ds_read_b128 + float4 stores, fully contiguous.

#define A_    3
#define H_    80
#define W_    80
#define CH_   85          // 5 + 80 classes
#define TILE_ (CH_ * W_)  // 6800 floats per (b,a,y)

__device__ __forceinline__ float fast_sigmoid(float x) {
    // v_exp_f32 + v_rcp_f32; rel err ~1e-6, far under the 2% absmax threshold.
    return __builtin_amdgcn_rcpf(1.0f + __expf(-x));
}

__global__ __launch_bounds__(256) void yolo_head_kernel(
    const float* __restrict__ in,
    const float* __restrict__ anchors,
    float* __restrict__ out)
{
    __shared__ float lds[TILE_];

    const int bid = blockIdx.x;        // (b*3 + a)*80 + y
    const int y   = bid % H_;
    const int ba  = bid / H_;          // b*3 + a  (input channel base = ba*85)
    const int a   = ba % A_;

    const float aw = anchors[2 * a];
    const float ah = anchors[2 * a + 1];
    const float fy = (float)y;
    const int   t  = threadIdx.x;

    // ---- Phase 1: global (ch-major) -> transform -> LDS (x-major) ----
    // in[(ba*85 + ch)*6400 + y*80 + x]
    const int in_base = (ba * CH_) * (H_ * W_) + y * W_;
#pragma unroll
    for (int k = 0; k < 27; ++k) {
        int i = k * 256 + t;           // i = ch*80 + x
        if (i < TILE_) {
            int ch = i / W_;
            int x  = i - ch * W_;
            float v = in[in_base + ch * (H_ * W_) + x];
            float r;
            if (ch >= 4) {
                r = fast_sigmoid(v);                       // conf + classes
            } else if (ch == 0) {
                r = (fast_sigmoid(v) + (float)x) * 8.0f;   // px, stride_w = 8
            } else if (ch == 1) {
                r = (fast_sigmoid(v) + fy) * 8.0f;         // py, stride_h = 8
            } else {
                float c = fminf(fmaxf(v, -16.0f), 16.0f);
                r = __expf(c) * ((ch == 2) ? aw : ah);     // pw / ph
            }
            lds[x * CH_ + ch] = r;     // bank stride 85 % 32 = 21 -> conflict-free
        }
    }
    __syncthreads();

    // ---- Phase 2: LDS -> out, contiguous float4 ----
    float4*       out4 = (float4*)(out + bid * TILE_);     // bid*27200 B, 16B-aligned
    const float4* lds4 = (const float4*)lds;
#pragma unroll
    for (int k = 0; k < 7; ++k) {
        int c = k * 256 + t;
        if (c < TILE_ / 4) {
            out4[c] = lds4[c];
        }
    }
}

extern "C" void kernel_launch(void* const* d_in, const int* in_sizes, int n_in,
                              void* d_out, int out_size, void* d_ws, size_t ws_size,
                              hipStream_t stream) {
    const float* in      = (const float*)d_in[0];   // (16, 255, 80, 80) fp32
    const float* anchors = (const float*)d_in[1];   // (3, 2) fp32
    float*       out     = (float*)d_out;           // (16, 19200, 85) fp32

    const int blocks = 16 * A_ * H_;                // 3840: one per (b,a,y)
    yolo_head_kernel<<<blocks, 256, 0, stream>>>(in, anchors, out);
}

// Round 3
// 185.227 us; speedup vs baseline: 1.0216x; 1.0216x over previous
//
#include <hip/hip_runtime.h>

// YOLOv7 P3 head (stride 8): B=16, A=3, NC=80, H=W=80.
// Input  (b, a*85, h, w) channel-major fp32.
// Output (b, a*h*w, 85)  fp32: [px,py,pw,ph,conf,cls*80].
//
// One block per (b,a,y): output block = 6800 contiguous floats at bid*6800.
// 512 threads/block: 4 blocks x 8 waves = 32 waves/CU (100% occupancy cap).
// Phase 1: float4 global loads along x -> transform -> 4 scalar LDS writes
//          in output order lds[x*85+ch].
// Phase 2: contiguous LDS reads -> nontemporal 16B stores (native ext_vector
//          type: __builtin_nontemporal_store rejects HIP_vector_type).

#define A_    3
#define H_    80
#define W_    80
#define CH_   85            // 5 + 80 classes
#define TILE_ (CH_ * W_)    // 6800 floats per (b,a,y)
#define VEC_  (TILE_ / 4)   // 1700 float4

typedef float f32x4 __attribute__((ext_vector_type(4)));

__device__ __forceinline__ float fast_sigmoid(float x) {
    return __builtin_amdgcn_rcpf(1.0f + __expf(-x));
}

__global__ __launch_bounds__(512) void yolo_head_kernel(
    const float* __restrict__ in,
    const float* __restrict__ anchors,
    float* __restrict__ out)
{
    __shared__ float lds[TILE_];

    const int bid = blockIdx.x;        // (b*3 + a)*80 + y
    const int y   = bid % H_;
    const int ba  = bid / H_;          // b*3 + a
    const int a   = ba % A_;

    const float aw = anchors[2 * a];
    const float ah = anchors[2 * a + 1];
    const float fy = (float)y;
    const int   t  = threadIdx.x;

    // ---- Phase 1: global float4 (ch-major) -> transform -> LDS (x-major) ----
    // in[(ba*85 + ch)*6400 + y*80 + x], x = 4*xq + j
    const float* in_row = in + (size_t)(ba * CH_) * (H_ * W_) + y * W_;
#pragma unroll
    for (int k = 0; k < 4; ++k) {
        int i = k * 512 + t;           // i = ch*20 + xq
        if (i < VEC_) {
            int ch = i / 20;
            int xq = i - ch * 20;
            f32x4 v = *(const f32x4*)(in_row + ch * (H_ * W_) + 4 * xq);
            float r[4];
            if (ch >= 4) {
                r[0] = fast_sigmoid(v.x);
                r[1] = fast_sigmoid(v.y);
                r[2] = fast_sigmoid(v.z);
                r[3] = fast_sigmoid(v.w);
            } else if (ch == 0) {
                float x0 = (float)(4 * xq);
                r[0] = (fast_sigmoid(v.x) + x0)        * 8.0f;  // px
                r[1] = (fast_sigmoid(v.y) + x0 + 1.0f) * 8.0f;
                r[2] = (fast_sigmoid(v.z) + x0 + 2.0f) * 8.0f;
                r[3] = (fast_sigmoid(v.w) + x0 + 3.0f) * 8.0f;
            } else if (ch == 1) {
                r[0] = (fast_sigmoid(v.x) + fy) * 8.0f;         // py
                r[1] = (fast_sigmoid(v.y) + fy) * 8.0f;
                r[2] = (fast_sigmoid(v.z) + fy) * 8.0f;
                r[3] = (fast_sigmoid(v.w) + fy) * 8.0f;
            } else {
                float s = (ch == 2) ? aw : ah;                  // pw / ph
                r[0] = __expf(fminf(fmaxf(v.x, -16.0f), 16.0f)) * s;
                r[1] = __expf(fminf(fmaxf(v.y, -16.0f), 16.0f)) * s;
                r[2] = __expf(fminf(fmaxf(v.z, -16.0f), 16.0f)) * s;
                r[3] = __expf(fminf(fmaxf(v.w, -16.0f), 16.0f)) * s;
            }
            int base = 4 * xq * CH_ + ch;   // lds[(4*xq+j)*85 + ch]
#pragma unroll
            for (int j = 0; j < 4; ++j)
                lds[base + j * CH_] = r[j];
        }
    }
    __syncthreads();

    // ---- Phase 2: LDS -> out, contiguous 16B nontemporal stores ----
    f32x4*       out4 = (f32x4*)(out + (size_t)bid * TILE_);
    const f32x4* lds4 = (const f32x4*)lds;
#pragma unroll
    for (int k = 0; k < 4; ++k) {
        int c = k * 512 + t;
        if (c < VEC_) {
            __builtin_nontemporal_store(lds4[c], &out4[c]);
        }
    }
}

extern "C" void kernel_launch(void* const* d_in, const int* in_sizes, int n_in,
                              void* d_out, int out_size, void* d_ws, size_t ws_size,
                              hipStream_t stream) {
    const float* in      = (const float*)d_in[0];   // (16, 255, 80, 80) fp32
    const float* anchors = (const float*)d_in[1];   // (3, 2) fp32
    float*       out     = (float*)d_out;           // (16, 19200, 85) fp32

    const int blocks = 16 * A_ * H_;                // 3840: one per (b,a,y)
    yolo_head_kernel<<<blocks, 512, 0, stream>>>(in, anchors, out);
}